// Round 1
// baseline (439.493 us; speedup 1.0000x reference)
//
#include <hip/hip_runtime.h>
#include <math.h>

#define DIM 1280
#define NDIM 8
#define CHUNKS 5   // 5 chunks * 64 lanes * 4 floats = 1280

__global__ __launch_bounds__(256, 2)
void fsq_kernel(const float* __restrict__ x, const float* __restrict__ W,
                const float* __restrict__ b, int* __restrict__ out, int n_tok) {
    const int lane    = threadIdx.x & 63;
    const int wave    = (int)((blockIdx.x * blockDim.x + threadIdx.x) >> 6);
    const int n_waves = (int)((gridDim.x * blockDim.x) >> 6);

    // digit = +1 iff tanh(h)*SCALE > 0.5  <=>  h > atanh(0.5/SCALE)
    const float T = (float)atanh(0.5 / 0.9990000128746033);

    // Preload W fragments into registers: w[c][k] = W[k][c*256 + lane*4 .. +3]
    float4 w[CHUNKS][NDIM];
    #pragma unroll
    for (int c = 0; c < CHUNKS; ++c) {
        #pragma unroll
        for (int k = 0; k < NDIM; ++k) {
            w[c][k] = *(const float4*)(W + k * DIM + c * 256 + lane * 4);
        }
    }

    // Per-lane k assignment from lane bits 5,4,3 — matches the butterfly's
    // k-splitting order below (off=32 splits k by 4, off=16 by 2, off=8 by 1).
    const int b5 = (lane >> 5) & 1;
    const int b4 = (lane >> 4) & 1;
    const int b3 = (lane >> 3) & 1;
    const int kk = 4 * b5 + 2 * b4 + b3;
    const float bk  = b[kk];
    const int   p3k = (kk & 1 ? 3 : 1) * (kk & 2 ? 9 : 1) * (kk & 4 ? 81 : 1);

    if (wave >= n_tok) return;

    // Initial token load
    float4 xv[CHUNKS];
    {
        const float4* xp = (const float4*)(x + (size_t)wave * DIM);
        #pragma unroll
        for (int c = 0; c < CHUNKS; ++c) xv[c] = xp[c * 64 + lane];
    }

    for (int t = wave; t < n_tok; t += n_waves) {
        float acc[NDIM];
        #pragma unroll
        for (int k = 0; k < NDIM; ++k) acc[k] = 0.0f;

        #pragma unroll
        for (int c = 0; c < CHUNKS; ++c) {
            #pragma unroll
            for (int k = 0; k < NDIM; ++k) {
                acc[k] = fmaf(xv[c].x, w[c][k].x, acc[k]);
                acc[k] = fmaf(xv[c].y, w[c][k].y, acc[k]);
                acc[k] = fmaf(xv[c].z, w[c][k].z, acc[k]);
                acc[k] = fmaf(xv[c].w, w[c][k].w, acc[k]);
            }
        }

        // xv is dead now: prefetch the NEXT token's x so the 5 global loads
        // overlap the shuffle-reduce below (and the next iter's waitcnt).
        const int tn = t + n_waves;
        if (tn < n_tok) {
            const float4* xp = (const float4*)(x + (size_t)tn * DIM);
            #pragma unroll
            for (int c = 0; c < CHUNKS; ++c) xv[c] = xp[c * 64 + lane];
        }

        // k-splitting butterfly: stage order 32,16,8,4,2,1 is IDENTICAL to the
        // full per-k butterfly, and each stage computes the same two-operand
        // sums (addition is commutative), so every per-k dot is bit-identical
        // to the previous kernel. 13 shuffles/token instead of 48.
        float r4[4];
        #pragma unroll
        for (int i = 0; i < 4; ++i) {
            float keep = b5 ? acc[i + 4] : acc[i];
            float send = b5 ? acc[i]     : acc[i + 4];
            r4[i] = keep + __shfl_xor(send, 32, 64);
        }
        float r2[2];
        #pragma unroll
        for (int j = 0; j < 2; ++j) {
            float keep = b4 ? r4[j + 2] : r4[j];
            float send = b4 ? r4[j]     : r4[j + 2];
            r2[j] = keep + __shfl_xor(send, 16, 64);
        }
        float s;
        {
            float keep = b3 ? r2[1] : r2[0];
            float send = b3 ? r2[0] : r2[1];
            s = keep + __shfl_xor(send, 8, 64);
        }
        s += __shfl_xor(s, 4, 64);
        s += __shfl_xor(s, 2, 64);
        s += __shfl_xor(s, 1, 64);

        // Each lane now holds the fully-reduced dot for its k = kk.
        const float h = s + bk;
        const int   d = 1 + (h > T ? 1 : 0) - (h < -T ? 1 : 0);  // {0,1,2}
        int mu = d * p3k;
        // Sum the 8 digit terms (lanes differing in bits 3..5 cover all k).
        mu += __shfl_xor(mu, 32, 64);
        mu += __shfl_xor(mu, 16, 64);
        mu += __shfl_xor(mu, 8, 64);
        if (lane == 0) out[t] = mu;
    }
}

extern "C" void kernel_launch(void* const* d_in, const int* in_sizes, int n_in,
                              void* d_out, int out_size, void* d_ws, size_t ws_size,
                              hipStream_t stream) {
    const float* x = (const float*)d_in[0];   // (B*T, 1280) fp32
    const float* W = (const float*)d_in[1];   // (8, 1280) fp32
    const float* b = (const float*)d_in[2];   // (8,) fp32
    int* out = (int*)d_out;                   // (B*T,) int32

    const int n_tok = in_sizes[0] / DIM;      // 65536
    const int blocks = 1024;                  // 4096 waves -> 16 tokens/wave
    fsq_kernel<<<blocks, 256, 0, stream>>>(x, W, b, out, n_tok);
}